// Round 13
// baseline (174.449 us; speedup 1.0000x reference)
//
#include <hip/hip_runtime.h>

// P2B_XCorr: B=8, F=128, M=256, N=1024, H=64, O=128. fp32 I/O.
// R20 = R19 with 6-wave blocks (one lever: +50% waves/SIMD).
//   R19 post-mortem: k_main fell below the harness's 256MiB re-poison fills
//   (41us each) in top-5 -> k_main <=40.7us; the stable ~117us residue across
//   all rounds is harness-side (fills + memsets + aux ~15us). k_main remains
//   the only lever; both pipes <35% busy = latency/TLP structure.
//   Fix: 384-thread blocks (6 waves), m 6-way split (m = mc*6 + w):
//   grid (64,8) = 512 blocks x 6 waves = 3072 waves = 12 waves/CU uniform
//   (2 blk/CU, no straggler) at __launch_bounds__(384,3) -> 3 waves/SIMD,
//   ~170-reg cap fits the measured ~148-reg live set. Waves 0-3: 43 iters,
//   waves 4-5: 42 + one clamped repeat (max is idempotent). 6-way LDS combine.
// R16 core (kept): L3 K32 B-frags ARE packed L2 relu outputs via PERMUTED W3
//   prepack (slot (kk,q,j) <-> g = kk*32 + (j<4 ? q*4+j : 16+q*4+j-4));
//   no in-loop LDS; L3 lags one iter (e0P/e1P); c3 deferred; triple-buffer
//   prefetch (A/B/C, ~3-iter load->use distance).
// Frag layouts (HW-verified): A[m=lane&15][k=quad*8+j],
// B[k=quad*8+j][n=lane&15], D[row=quad*4+reg][col=lane&15].

#define BB 8
#define FF 128
#define MM 256
#define NN 1024
#define HH 64
#define OO 128
#define BN_EPS 1e-5f
#define COS_EPS 1e-8f

// ws layout (float offsets); total 2,251,008 floats = 8.59 MiB (proven envelope)
#define WS_U     0
#define WS_C2    64
#define WS_C3    128
#define WS_CC1   192
#define WS_W2H   256          // f16 [64][64] folded a2*W2 (2048 float slots)
#define WS_W3H   2304         // f16 [64][64] folded a3*W3, k-slot PERMUTED
#define WS_WC1F  8448
#define WS_A1    12544        // f16 A1H[b][m][64]
#define WS_NT    143616       // [b][m] fp32 (NS contiguous after)
#define WS_NS    145664       // [b][n] fp32
#define WS_COSH  153856       // f16 cos[b][m][n]
#define WS_P     1202432      // fp32 single slice [b][n][64]

typedef _Float16 half2v __attribute__((ext_vector_type(2)));
typedef _Float16 half8  __attribute__((ext_vector_type(8)));
typedef __attribute__((ext_vector_type(4))) float f32x4;

__device__ __forceinline__ unsigned int pkh2(float a, float b){
  auto h = __builtin_amdgcn_cvt_pkrtz(a, b);
  return __builtin_bit_cast(unsigned int, h);
}
__device__ __forceinline__ half2v u2h(unsigned int u){
  return __builtin_bit_cast(half2v, u);
}
__device__ __forceinline__ unsigned int h2u(half2v v){
  return __builtin_bit_cast(unsigned int, v);
}
__device__ __forceinline__ unsigned int relu2(unsigned int d){
  half2v v = __builtin_elementwise_max(u2h(d), (half2v){(_Float16)0, (_Float16)0});
  return h2u(v);
}
__device__ __forceinline__ unsigned int bh1(unsigned int up, half2v c, unsigned int ap){
  half2v v = __builtin_elementwise_fma(u2h(up), c, u2h(ap));
  v = __builtin_elementwise_max(v, (half2v){(_Float16)0, (_Float16)0});
  return h2u(v);
}
__device__ __forceinline__ float dot4(float4 a, float4 b, float acc){
  acc = fmaf(a.x, b.x, acc); acc = fmaf(a.y, b.y, acc);
  acc = fmaf(a.z, b.z, acc); acc = fmaf(a.w, b.w, acc);
  return acc;
}

// ---------------- K1: prep (role-split: a1 | norms | fold) ----------------
__global__ __launch_bounds__(256) void k_prep(const float* t_, const float* s_,
    const float* W1, const float* W2, const float* W3, const float* Wc1,
    const float* g1, const float* b1, const float* m1, const float* v1,
    const float* g2, const float* b2, const float* m2, const float* v2,
    const float* g3, const float* b3, const float* m3, const float* v3,
    const float* gc1,const float* bc1,const float* mc1,const float* vc1,
    float* ws){
  __shared__ float W1s[64][133];
  int t = threadIdx.x;
  int bx = blockIdx.x;
  if (bx < 256){
    // ---- A1H[b][m][h] (f16) ----
    int b = bx >> 5, m0 = (bx & 31)*8;
    for (int idx = t; idx < 8192; idx += 256){
      int h = idx >> 7, f = idx & 127;
      W1s[h][f] = W1[h*129 + 1 + f];
    }
    __syncthreads();
    int h = t & 63, mg = t >> 6;
    const float* tp = t_ + (size_t)b*FF*MM + m0 + mg*2;
    float acc0 = 0.f, acc1 = 0.f;
    for (int f = 0; f < FF; f++){
      float wv = W1s[h][f];
      float2 tv = *(const float2*)&tp[(size_t)f*MM];
      acc0 = fmaf(wv, tv.x, acc0); acc1 = fmaf(wv, tv.y, acc1);
    }
    float a1 = g1[h] / sqrtf(v1[h] + BN_EPS);
    float c1 = b1[h] - a1*m1[h];
    unsigned short* dst = (unsigned short*)(ws + WS_A1) + ((size_t)(b*MM + m0 + mg*2))*64 + h;
    dst[0]  = (unsigned short)(pkh2(fmaf(a1, acc0, c1), 0.f) & 0xFFFFu);
    dst[64] = (unsigned short)(pkh2(fmaf(a1, acc1, c1), 0.f) & 0xFFFFu);
  } else if (bx < 416){
    // ---- norms ----
    __shared__ float red[4][64];
    int x = t & 63, fq = t >> 6;
    int idx = (bx - 256)*64 + x;
    const float* ptr; size_t stride;
    if (idx < BB*MM){
      int b = idx >> 8, m = idx & 255;
      ptr = t_ + (size_t)b*FF*MM + m; stride = MM;
    } else {
      int j = idx - BB*MM;
      int b = j >> 10, n = j & 1023;
      ptr = s_ + (size_t)b*FF*NN + n; stride = NN;
    }
    float acc = 0.f;
    for (int f = fq*32; f < fq*32 + 32; f++){
      float v = ptr[(size_t)f*stride]; acc = fmaf(v, v, acc);
    }
    red[fq][x] = acc;
    __syncthreads();
    if (fq == 0)
      ws[WS_NT + idx] = sqrtf(red[0][x] + red[1][x] + red[2][x] + red[3][x]);
  } else {
    // ---- fold ----
    if (t < 64){
      float a1 = g1[t] / sqrtf(v1[t] + BN_EPS);
      ws[WS_U + t]   = a1 * W1[t*129];
      float a2 = g2[t] / sqrtf(v2[t] + BN_EPS);
      ws[WS_C2 + t]  = b2[t] - a2*m2[t];
      float a3 = g3[t] / sqrtf(v3[t] + BN_EPS);
      ws[WS_C3 + t]  = b3[t] - a3*m3[t];
      float ac = gc1[t] / sqrtf(vc1[t] + BN_EPS);
      ws[WS_CC1 + t] = bc1[t] - ac*mc1[t];
    }
    unsigned short* w2h = (unsigned short*)(ws + WS_W2H);
    unsigned short* w3h = (unsigned short*)(ws + WS_W3H);
    for (int i = t; i < 4096; i += 256){
      int gp = i >> 6;
      float a2 = g2[gp] / sqrtf(v2[gp] + BN_EPS);
      w2h[i] = __builtin_bit_cast(unsigned short, (_Float16)(a2 * W2[i]));
      // W3: k-slot permuted. slot s = kk*32 + q*8 + j  <->
      //   g = kk*32 + (j<4 ? q*4+j : 16 + q*4 + (j-4))
      {
        int s = i & 63;
        int kk = s >> 5, s2 = s & 31, q = s2 >> 3, j = s2 & 7;
        int g = kk*32 + ((j < 4) ? (q*4 + j) : (16 + q*4 + (j - 4)));
        float a3 = g3[gp] / sqrtf(v3[gp] + BN_EPS);
        w3h[i] = __builtin_bit_cast(unsigned short, (_Float16)(a3 * W3[gp*64 + g]));
      }
      float ac = gc1[gp] / sqrtf(vc1[gp] + BN_EPS);
      ws[WS_WC1F + i] = ac * Wc1[i];
    }
  }
}

// ---------------- K2: cos via f16 MFMA, swapped operands (D rows = n) ----------------
__global__ __launch_bounds__(256) void k_cos(const float* t_, const float* s_, float* ws){
  __shared__ __align__(16) unsigned short tS[64][136];
  __shared__ __align__(16) unsigned short sS[64][136];
  __shared__ float ntS[64], nsS[64];
  int t = threadIdx.x;
  int lane = t & 63, w = t >> 6;
  int ln15 = lane & 15, quad = lane >> 4;
  int m0 = blockIdx.x*64, n0 = blockIdx.y*64, b = blockIdx.z;
  {
    int x = t & 63;
    const float* tb = t_ + (size_t)b*FF*MM + m0 + x;
    const float* sb = s_ + (size_t)b*FF*NN + n0 + x;
    #pragma unroll
    for (int k = 0; k < 16; k++){
      int fp = w*16 + k;
      *(unsigned int*)&tS[x][2*fp] = pkh2(tb[(size_t)(2*fp)*MM], tb[(size_t)(2*fp+1)*MM]);
      *(unsigned int*)&sS[x][2*fp] = pkh2(sb[(size_t)(2*fp)*NN], sb[(size_t)(2*fp+1)*NN]);
    }
    if (t < 64) ntS[t] = ws[WS_NT + b*MM + m0 + t];
    else if (t < 128) nsS[t-64] = ws[WS_NS + b*NN + n0 + (t-64)];
  }
  __syncthreads();
  // A = s (rows -> n), per-wave n-tile w
  half8 A4[4];
  #pragma unroll
  for (int kc = 0; kc < 4; kc++)
    A4[kc] = *(const half8*)&sS[w*16 + ln15][kc*32 + quad*8];
  float4 ns4 = *(const float4*)&nsS[w*16 + quad*4];
  int nb = n0 + w*16 + quad*4;                       // 4 consecutive n per lane
  unsigned short* cosw = (unsigned short*)(ws + WS_COSH);
  #pragma unroll
  for (int mt = 0; mt < 4; mt++){
    f32x4 acc = (f32x4){0.f,0.f,0.f,0.f};
    #pragma unroll
    for (int kc = 0; kc < 4; kc++){
      half8 B4 = *(const half8*)&tS[mt*16 + ln15][kc*32 + quad*8];
      acc = __builtin_amdgcn_mfma_f32_16x16x32_f16(A4[kc], B4, acc, 0, 0, 0);
    }
    int m = m0 + mt*16 + ln15;
    float ntv = ntS[mt*16 + ln15];
    float c0 = acc[0] * __builtin_amdgcn_rcpf(fmaxf(ntv*ns4.x, COS_EPS));
    float c1 = acc[1] * __builtin_amdgcn_rcpf(fmaxf(ntv*ns4.y, COS_EPS));
    float c2 = acc[2] * __builtin_amdgcn_rcpf(fmaxf(ntv*ns4.z, COS_EPS));
    float c3 = acc[3] * __builtin_amdgcn_rcpf(fmaxf(ntv*ns4.w, COS_EPS));
    uint2 vv;
    vv.x = pkh2(c0, c1);
    vv.y = pkh2(c2, c3);
    *(uint2*)&cosw[(size_t)(b*MM + m)*NN + nb] = vv;
  }
}

// ---------------- K3: main. grid (64,8), 6 waves; wave w: m = mc*6 + w ----------------
// All-register; TRIPLE-buffer prefetch; waves 4,5 repeat their last m once (max idempotent).
#define K_LD(mi, cu_, aa, ab) { \
  int mm_ = (((mi) < mcMax) ? (mi) : mcMax)*6 + w; \
  cu_ = cosP[(size_t)mm_*NN]; \
  aa = *(const uint4*)&A1H[(size_t)mm_*64 + quad*8]; \
  ab = *(const uint4*)&A1H[(size_t)mm_*64 + 32 + quad*8]; }

#define K_STEP(cu_, aa, ab) { \
  unsigned int cd_ = (cu_) | ((cu_) << 16); \
  half2v ch_ = u2h(cd_); \
  uint4 q0_, q1_; \
  q0_.x = bh1(upk[0][0], ch_, (aa).x); q0_.y = bh1(upk[0][1], ch_, (aa).y); \
  q0_.z = bh1(upk[0][2], ch_, (aa).z); q0_.w = bh1(upk[0][3], ch_, (aa).w); \
  q1_.x = bh1(upk[1][0], ch_, (ab).x); q1_.y = bh1(upk[1][1], ch_, (ab).y); \
  q1_.z = bh1(upk[1][2], ch_, (ab).z); q1_.w = bh1(upk[1][3], ch_, (ab).w); \
  half8 b0h_ = __builtin_bit_cast(half8, q0_); \
  half8 b1h_ = __builtin_bit_cast(half8, q1_); \
  f32x4 a0_, a1_, a2_, a3x_; \
  a0_ = __builtin_amdgcn_mfma_f32_16x16x32_f16(W2A[0][0], b0h_, c2v[0], 0, 0, 0); \
  a0_ = __builtin_amdgcn_mfma_f32_16x16x32_f16(W2A[0][1], b1h_, a0_, 0, 0, 0); \
  a1_ = __builtin_amdgcn_mfma_f32_16x16x32_f16(W2A[1][0], b0h_, c2v[1], 0, 0, 0); \
  a1_ = __builtin_amdgcn_mfma_f32_16x16x32_f16(W2A[1][1], b1h_, a1_, 0, 0, 0); \
  a2_ = __builtin_amdgcn_mfma_f32_16x16x32_f16(W2A[2][0], b0h_, c2v[2], 0, 0, 0); \
  a2_ = __builtin_amdgcn_mfma_f32_16x16x32_f16(W2A[2][1], b1h_, a2_, 0, 0, 0); \
  a3x_ = __builtin_amdgcn_mfma_f32_16x16x32_f16(W2A[3][0], b0h_, c2v[3], 0, 0, 0); \
  a3x_ = __builtin_amdgcn_mfma_f32_16x16x32_f16(W2A[3][1], b1h_, a3x_, 0, 0, 0); \
  e0P.x = relu2(pkh2(a0_[0], a0_[1])); e0P.y = relu2(pkh2(a0_[2], a0_[3])); \
  e0P.z = relu2(pkh2(a1_[0], a1_[1])); e0P.w = relu2(pkh2(a1_[2], a1_[3])); \
  e1P.x = relu2(pkh2(a2_[0], a2_[1])); e1P.y = relu2(pkh2(a2_[2], a2_[3])); \
  e1P.z = relu2(pkh2(a3x_[0], a3x_[1])); e1P.w = relu2(pkh2(a3x_[2], a3x_[3])); }

#define K_L3 { \
  half8 pe0_ = __builtin_bit_cast(half8, e0P); \
  half8 pe1_ = __builtin_bit_cast(half8, e1P); \
  _Pragma("unroll") \
  for (int rt = 0; rt < 4; rt++){ \
    f32x4 a3_ = __builtin_amdgcn_mfma_f32_16x16x32_f16(W3A[rt][0], pe0_, zf, 0, 0, 0); \
    a3_ = __builtin_amdgcn_mfma_f32_16x16x32_f16(W3A[rt][1], pe1_, a3_, 0, 0, 0); \
    _Pragma("unroll") \
    for (int r = 0; r < 4; r++) p[rt][r] = fmaxf(p[rt][r], a3_[r]); \
  } }

__global__ __launch_bounds__(384, 3) void k_main(const float* ws, float* Pp){
  __shared__ __align__(16) float redS[5][16][68];          // parked partials (waves 1..5)
  int t = threadIdx.x;
  int lane = t & 63, w = t >> 6;                     // w in 0..5
  int ln15 = lane & 15, quad = lane >> 4;
  int b = blockIdx.y;
  int n0 = blockIdx.x * 16;
  int mcMax = (w < 4) ? 42 : 41;                     // last valid mc for this wave

  // weight A-frags (prepacked f16; W3 slot-permuted) + layer-2 bias C (c3 deferred)
  const unsigned short* w2h = (const unsigned short*)(ws + WS_W2H);
  const unsigned short* w3h = (const unsigned short*)(ws + WS_W3H);
  half8 W2A[4][2], W3A[4][2];
  f32x4 c2v[4];
  #pragma unroll
  for (int rt = 0; rt < 4; rt++){
    int g = rt*16 + ln15;
    #pragma unroll
    for (int kk = 0; kk < 2; kk++){
      W2A[rt][kk] = *(const half8*)&w2h[g*64 + kk*32 + quad*8];
      W3A[rt][kk] = *(const half8*)&w3h[g*64 + kk*32 + quad*8];
    }
    float4 cb2 = *(const float4*)&ws[WS_C2 + rt*16 + quad*4];
    c2v[rt] = (f32x4){cb2.x, cb2.y, cb2.z, cb2.w};
  }
  f32x4 zf = (f32x4){0.f, 0.f, 0.f, 0.f};
  // u[h] packed pairs for this lane's h-chunks
  unsigned int upk[2][4];
  #pragma unroll
  for (int kk = 0; kk < 2; kk++){
    float4 ua = *(const float4*)&ws[WS_U + kk*32 + quad*8];
    float4 ub = *(const float4*)&ws[WS_U + kk*32 + quad*8 + 4];
    upk[kk][0] = pkh2(ua.x, ua.y); upk[kk][1] = pkh2(ua.z, ua.w);
    upk[kk][2] = pkh2(ub.x, ub.y); upk[kk][3] = pkh2(ub.z, ub.w);
  }
  const unsigned short* A1H = (const unsigned short*)(ws + WS_A1) + (size_t)b*MM*64;
  int n = n0 + ln15;                                // this lane's n (shared by all waves)
  const unsigned short* cosP = (const unsigned short*)(ws + WS_COSH)
                               + (size_t)b*MM*NN + n;

  f32x4 p[4];
  #pragma unroll
  for (int rt = 0; rt < 4; rt++)
    p[rt] = (f32x4){-3.0e38f, -3.0e38f, -3.0e38f, -3.0e38f};

  uint4 e0P, e1P;   // packed h2 of previous iter = L3 K32 B-frags

  // triple-buffer state: A=m(3k), B=m(3k+1), C=m(3k+2) rotation
  unsigned int cuA, cuB, cuC;
  uint4 a1aA, a1bA, a1aB, a1bB, a1aC, a1bC;

  K_LD(0, cuA, a1aA, a1bA)
  K_LD(1, cuB, a1aB, a1bB)
  K_LD(2, cuC, a1aC, a1bC)

  // iter 0: h1+L2+pack; refill A with m3 (~3-iter distance to its use)
  K_STEP(cuA, a1aA, a1bA)
  K_LD(3, cuA, a1aA, a1bA)

  // iters 1..42 in 14 triplets: m(3k+1), m(3k+2), m(3k+3); refills 3 ahead.
  // Waves 4,5 (mcMax=41) repeat mc=41 once at the clamped end: max idempotent.
  for (int k = 0; k < 14; k++){
    K_L3
    K_STEP(cuB, a1aB, a1bB)
    K_LD(3*k + 4, cuB, a1aB, a1bB)
    K_L3
    K_STEP(cuC, a1aC, a1bC)
    K_LD(3*k + 5, cuC, a1aC, a1bC)
    K_L3
    K_STEP(cuA, a1aA, a1bA)
    K_LD(3*k + 6, cuA, a1aA, a1bA)
  }
  // final L3 (of iter 42)
  K_L3

  // 6-way cross-wave max combine: waves 1..5 park raw p, wave 0 merges,
  // applies deferred c3 + relu, stores final P (single slice).
  __syncthreads();
  if (w >= 1){
    #pragma unroll
    for (int rt = 0; rt < 4; rt++){
      f32x4 v = p[rt];
      *(float4*)&redS[w-1][ln15][rt*16 + quad*4] = make_float4(v[0], v[1], v[2], v[3]);
    }
  }
  __syncthreads();
  if (w == 0){
    float* Pb = Pp + ((size_t)(b*NN + n) << 6);
    #pragma unroll
    for (int rt = 0; rt < 4; rt++){
      float4 o1 = *(const float4*)&redS[0][ln15][rt*16 + quad*4];
      float4 o2 = *(const float4*)&redS[1][ln15][rt*16 + quad*4];
      float4 o3 = *(const float4*)&redS[2][ln15][rt*16 + quad*4];
      float4 o4 = *(const float4*)&redS[3][ln15][rt*16 + quad*4];
      float4 o5 = *(const float4*)&redS[4][ln15][rt*16 + quad*4];
      float4 c3b = *(const float4*)&ws[WS_C3 + rt*16 + quad*4];
      float4 r4;
      r4.x = fmaxf(fmaxf(fmaxf(p[rt][0], o1.x), fmaxf(o2.x, o3.x)), fmaxf(o4.x, o5.x));
      r4.y = fmaxf(fmaxf(fmaxf(p[rt][1], o1.y), fmaxf(o2.y, o3.y)), fmaxf(o4.y, o5.y));
      r4.z = fmaxf(fmaxf(fmaxf(p[rt][2], o1.z), fmaxf(o2.z, o3.z)), fmaxf(o4.z, o5.z));
      r4.w = fmaxf(fmaxf(fmaxf(p[rt][3], o1.w), fmaxf(o2.w, o3.w)), fmaxf(o4.w, o5.w));
      r4.x = fmaxf(r4.x + c3b.x, 0.f);
      r4.y = fmaxf(r4.y + c3b.y, 0.f);
      r4.z = fmaxf(r4.z + c3b.z, 0.f);
      r4.w = fmaxf(r4.w + c3b.w, 0.f);
      *(float4*)&Pb[rt*16 + quad*4] = r4;
    }
  }
}

// ---------------- K4: tail (single P slice, Wc1f/relu, Wc2+bias) fp32 ----------------
__global__ __launch_bounds__(256) void k_tail(const float* Wc2, const float* bc2,
                                              const float* ws, float* out){
  __shared__ float WT[64][68];
  __shared__ float pT[32][68];
  __shared__ float cS[32][68];
  int t = threadIdx.x;
  int n0 = blockIdx.x * 32;
  int b = blockIdx.y;
  for (int i = t; i < 4096; i += 256) WT[i >> 6][i & 63] = ws[WS_WC1F + i];
  const float* P0 = ws + WS_P + ((size_t)(b*NN + n0) << 6);
  for (int i = t; i < 2048; i += 256) pT[i >> 6][i & 63] = P0[i];
  __syncthreads();
  {
    int n = t & 31, q = t >> 5;
    for (int k = 0; k < 8; k++){
      int g = q*8 + k;
      float acc = ws[WS_CC1 + g];
      for (int hs = 0; hs < 64; hs += 4){
        float4 wv = *(const float4*)&WT[g][hs];
        float4 pv = *(const float4*)&pT[n][hs];
        acc = dot4(wv, pv, acc);
      }
      cS[n][g] = fmaxf(acc, 0.f);
    }
  }
  __syncthreads();
  {
    int o = t & 127, hf = t >> 7;
    float bco = bc2[o];
    float accO[16];
    #pragma unroll
    for (int i = 0; i < 16; i++) accO[i] = bco;
    for (int hs = 0; hs < 64; hs += 4){
      float4 w4 = *(const float4*)&Wc2[o*64 + hs];
      #pragma unroll
      for (int i = 0; i < 16; i++){
        float4 cv = *(const float4*)&cS[hf*16 + i][hs];
        accO[i] = dot4(w4, cv, accO[i]);
      }
    }
    #pragma unroll
    for (int i = 0; i < 16; i++)
      out[((size_t)(b*OO + o))*NN + n0 + hf*16 + i] = accO[i];
  }
}

extern "C" void kernel_launch(void* const* d_in, const int* in_sizes, int n_in,
                              void* d_out, int out_size, void* d_ws, size_t ws_size,
                              hipStream_t stream){
  (void)in_sizes; (void)n_in; (void)out_size; (void)ws_size;
  const float* t_  = (const float*)d_in[0];
  const float* s_  = (const float*)d_in[1];
  const float* W1  = (const float*)d_in[2];
  const float* W2  = (const float*)d_in[3];
  const float* W3  = (const float*)d_in[4];
  const float* Wc1 = (const float*)d_in[5];
  const float* Wc2 = (const float*)d_in[6];
  const float* bc2 = (const float*)d_in[7];
  const float* g1 = (const float*)d_in[8],  *b1 = (const float*)d_in[9],
             * m1 = (const float*)d_in[10], *v1 = (const float*)d_in[11];
  const float* g2 = (const float*)d_in[12], *b2 = (const float*)d_in[13],
             * m2 = (const float*)d_in[14], *v2 = (const float*)d_in[15];
  const float* g3 = (const float*)d_in[16], *b3 = (const float*)d_in[17],
             * m3 = (const float*)d_in[18], *v3 = (const float*)d_in[19];
  const float* gc1 = (const float*)d_in[20], *bc1 = (const float*)d_in[21],
             * mc1 = (const float*)d_in[22], *vc1 = (const float*)d_in[23];
  float* ws = (float*)d_ws;
  float* out = (float*)d_out;

  k_prep<<<417, 256, 0, stream>>>(t_, s_, W1, W2, W3, Wc1,
      g1,b1,m1,v1, g2,b2,m2,v2, g3,b3,m3,v3, gc1,bc1,mc1,vc1, ws);
  k_cos<<<dim3(4, 16, 8), 256, 0, stream>>>(t_, s_, ws);
  k_main<<<dim3(64, 8), 384, 0, stream>>>(ws, ws + WS_P);
  k_tail<<<dim3(32, 8), 256, 0, stream>>>(Wc2, bc2, ws, out);
}

// Round 14
// 164.886 us; speedup vs baseline: 1.0580x; 1.0580x over previous
//
#include <hip/hip_runtime.h>

// P2B_XCorr: B=8, F=128, M=256, N=1024, H=64, O=128. fp32 I/O.
// R21 = R19 verbatim (best measured: 165.9us total; k_main ~40us).
//   R20 post-mortem: 6-wave blocks REGRESSED (53.4us, occ 15%) -- 6 waves
//   distribute 2/2/1/1 over 4 SIMDs, barrier spans 6 waves; wave-count levers
//   only help when block shape divides SIMD count. Occupancy space now fully
//   mapped: (256,3)+1024blk=47us straggler; (256,4)=spill 110us; 384thr=53us;
//   (256,2)+512blk uniform = best ~40us. Remaining k_main idle is latency-
//   structural at 2 waves/SIMD; remaining total cost (~117us: 256MiB re-poison
//   fills at 6.5TB/s + aux/launch fixed) is harness-side. Locking in R19.
// R19: grid (64,8) = 512 blocks x 64 m-iters, __launch_bounds__(256,2),
//   uniform 2 blk/CU; triple-buffer prefetch (A/B/C, ~3-iter load->use);
//   P single slice. R16 core: L3 K32 B-frags ARE packed L2 relu outputs via
//   PERMUTED W3 prepack (slot (kk,q,j) <-> g = kk*32 + (j<4 ? q*4+j
//   : 16+q*4+j-4)); no in-loop LDS; L3 lags one iter (e0P/e1P); c3 deferred.
// Frag layouts (HW-verified): A[m=lane&15][k=quad*8+j],
// B[k=quad*8+j][n=lane&15], D[row=quad*4+reg][col=lane&15].

#define BB 8
#define FF 128
#define MM 256
#define NN 1024
#define HH 64
#define OO 128
#define BN_EPS 1e-5f
#define COS_EPS 1e-8f

// ws layout (float offsets); total 2,251,008 floats = 8.59 MiB (proven envelope)
#define WS_U     0
#define WS_C2    64
#define WS_C3    128
#define WS_CC1   192
#define WS_W2H   256          // f16 [64][64] folded a2*W2 (2048 float slots)
#define WS_W3H   2304         // f16 [64][64] folded a3*W3, k-slot PERMUTED
#define WS_WC1F  8448
#define WS_A1    12544        // f16 A1H[b][m][64]
#define WS_NT    143616       // [b][m] fp32 (NS contiguous after)
#define WS_NS    145664       // [b][n] fp32
#define WS_COSH  153856       // f16 cos[b][m][n]
#define WS_P     1202432      // fp32 single slice [b][n][64]

typedef _Float16 half2v __attribute__((ext_vector_type(2)));
typedef _Float16 half8  __attribute__((ext_vector_type(8)));
typedef __attribute__((ext_vector_type(4))) float f32x4;

__device__ __forceinline__ unsigned int pkh2(float a, float b){
  auto h = __builtin_amdgcn_cvt_pkrtz(a, b);
  return __builtin_bit_cast(unsigned int, h);
}
__device__ __forceinline__ half2v u2h(unsigned int u){
  return __builtin_bit_cast(half2v, u);
}
__device__ __forceinline__ unsigned int h2u(half2v v){
  return __builtin_bit_cast(unsigned int, v);
}
__device__ __forceinline__ unsigned int relu2(unsigned int d){
  half2v v = __builtin_elementwise_max(u2h(d), (half2v){(_Float16)0, (_Float16)0});
  return h2u(v);
}
__device__ __forceinline__ unsigned int bh1(unsigned int up, half2v c, unsigned int ap){
  half2v v = __builtin_elementwise_fma(u2h(up), c, u2h(ap));
  v = __builtin_elementwise_max(v, (half2v){(_Float16)0, (_Float16)0});
  return h2u(v);
}
__device__ __forceinline__ float dot4(float4 a, float4 b, float acc){
  acc = fmaf(a.x, b.x, acc); acc = fmaf(a.y, b.y, acc);
  acc = fmaf(a.z, b.z, acc); acc = fmaf(a.w, b.w, acc);
  return acc;
}

// ---------------- K1: prep (role-split: a1 | norms | fold) ----------------
__global__ __launch_bounds__(256) void k_prep(const float* t_, const float* s_,
    const float* W1, const float* W2, const float* W3, const float* Wc1,
    const float* g1, const float* b1, const float* m1, const float* v1,
    const float* g2, const float* b2, const float* m2, const float* v2,
    const float* g3, const float* b3, const float* m3, const float* v3,
    const float* gc1,const float* bc1,const float* mc1,const float* vc1,
    float* ws){
  __shared__ float W1s[64][133];
  int t = threadIdx.x;
  int bx = blockIdx.x;
  if (bx < 256){
    // ---- A1H[b][m][h] (f16) ----
    int b = bx >> 5, m0 = (bx & 31)*8;
    for (int idx = t; idx < 8192; idx += 256){
      int h = idx >> 7, f = idx & 127;
      W1s[h][f] = W1[h*129 + 1 + f];
    }
    __syncthreads();
    int h = t & 63, mg = t >> 6;
    const float* tp = t_ + (size_t)b*FF*MM + m0 + mg*2;
    float acc0 = 0.f, acc1 = 0.f;
    for (int f = 0; f < FF; f++){
      float wv = W1s[h][f];
      float2 tv = *(const float2*)&tp[(size_t)f*MM];
      acc0 = fmaf(wv, tv.x, acc0); acc1 = fmaf(wv, tv.y, acc1);
    }
    float a1 = g1[h] / sqrtf(v1[h] + BN_EPS);
    float c1 = b1[h] - a1*m1[h];
    unsigned short* dst = (unsigned short*)(ws + WS_A1) + ((size_t)(b*MM + m0 + mg*2))*64 + h;
    dst[0]  = (unsigned short)(pkh2(fmaf(a1, acc0, c1), 0.f) & 0xFFFFu);
    dst[64] = (unsigned short)(pkh2(fmaf(a1, acc1, c1), 0.f) & 0xFFFFu);
  } else if (bx < 416){
    // ---- norms ----
    __shared__ float red[4][64];
    int x = t & 63, fq = t >> 6;
    int idx = (bx - 256)*64 + x;
    const float* ptr; size_t stride;
    if (idx < BB*MM){
      int b = idx >> 8, m = idx & 255;
      ptr = t_ + (size_t)b*FF*MM + m; stride = MM;
    } else {
      int j = idx - BB*MM;
      int b = j >> 10, n = j & 1023;
      ptr = s_ + (size_t)b*FF*NN + n; stride = NN;
    }
    float acc = 0.f;
    for (int f = fq*32; f < fq*32 + 32; f++){
      float v = ptr[(size_t)f*stride]; acc = fmaf(v, v, acc);
    }
    red[fq][x] = acc;
    __syncthreads();
    if (fq == 0)
      ws[WS_NT + idx] = sqrtf(red[0][x] + red[1][x] + red[2][x] + red[3][x]);
  } else {
    // ---- fold ----
    if (t < 64){
      float a1 = g1[t] / sqrtf(v1[t] + BN_EPS);
      ws[WS_U + t]   = a1 * W1[t*129];
      float a2 = g2[t] / sqrtf(v2[t] + BN_EPS);
      ws[WS_C2 + t]  = b2[t] - a2*m2[t];
      float a3 = g3[t] / sqrtf(v3[t] + BN_EPS);
      ws[WS_C3 + t]  = b3[t] - a3*m3[t];
      float ac = gc1[t] / sqrtf(vc1[t] + BN_EPS);
      ws[WS_CC1 + t] = bc1[t] - ac*mc1[t];
    }
    unsigned short* w2h = (unsigned short*)(ws + WS_W2H);
    unsigned short* w3h = (unsigned short*)(ws + WS_W3H);
    for (int i = t; i < 4096; i += 256){
      int gp = i >> 6;
      float a2 = g2[gp] / sqrtf(v2[gp] + BN_EPS);
      w2h[i] = __builtin_bit_cast(unsigned short, (_Float16)(a2 * W2[i]));
      // W3: k-slot permuted. slot s = kk*32 + q*8 + j  <->
      //   g = kk*32 + (j<4 ? q*4+j : 16 + q*4 + (j-4))
      {
        int s = i & 63;
        int kk = s >> 5, s2 = s & 31, q = s2 >> 3, j = s2 & 7;
        int g = kk*32 + ((j < 4) ? (q*4 + j) : (16 + q*4 + (j - 4)));
        float a3 = g3[gp] / sqrtf(v3[gp] + BN_EPS);
        w3h[i] = __builtin_bit_cast(unsigned short, (_Float16)(a3 * W3[gp*64 + g]));
      }
      float ac = gc1[gp] / sqrtf(vc1[gp] + BN_EPS);
      ws[WS_WC1F + i] = ac * Wc1[i];
    }
  }
}

// ---------------- K2: cos via f16 MFMA, swapped operands (D rows = n) ----------------
__global__ __launch_bounds__(256) void k_cos(const float* t_, const float* s_, float* ws){
  __shared__ __align__(16) unsigned short tS[64][136];
  __shared__ __align__(16) unsigned short sS[64][136];
  __shared__ float ntS[64], nsS[64];
  int t = threadIdx.x;
  int lane = t & 63, w = t >> 6;
  int ln15 = lane & 15, quad = lane >> 4;
  int m0 = blockIdx.x*64, n0 = blockIdx.y*64, b = blockIdx.z;
  {
    int x = t & 63;
    const float* tb = t_ + (size_t)b*FF*MM + m0 + x;
    const float* sb = s_ + (size_t)b*FF*NN + n0 + x;
    #pragma unroll
    for (int k = 0; k < 16; k++){
      int fp = w*16 + k;
      *(unsigned int*)&tS[x][2*fp] = pkh2(tb[(size_t)(2*fp)*MM], tb[(size_t)(2*fp+1)*MM]);
      *(unsigned int*)&sS[x][2*fp] = pkh2(sb[(size_t)(2*fp)*NN], sb[(size_t)(2*fp+1)*NN]);
    }
    if (t < 64) ntS[t] = ws[WS_NT + b*MM + m0 + t];
    else if (t < 128) nsS[t-64] = ws[WS_NS + b*NN + n0 + (t-64)];
  }
  __syncthreads();
  // A = s (rows -> n), per-wave n-tile w
  half8 A4[4];
  #pragma unroll
  for (int kc = 0; kc < 4; kc++)
    A4[kc] = *(const half8*)&sS[w*16 + ln15][kc*32 + quad*8];
  float4 ns4 = *(const float4*)&nsS[w*16 + quad*4];
  int nb = n0 + w*16 + quad*4;                       // 4 consecutive n per lane
  unsigned short* cosw = (unsigned short*)(ws + WS_COSH);
  #pragma unroll
  for (int mt = 0; mt < 4; mt++){
    f32x4 acc = (f32x4){0.f,0.f,0.f,0.f};
    #pragma unroll
    for (int kc = 0; kc < 4; kc++){
      half8 B4 = *(const half8*)&tS[mt*16 + ln15][kc*32 + quad*8];
      acc = __builtin_amdgcn_mfma_f32_16x16x32_f16(A4[kc], B4, acc, 0, 0, 0);
    }
    int m = m0 + mt*16 + ln15;
    float ntv = ntS[mt*16 + ln15];
    float c0 = acc[0] * __builtin_amdgcn_rcpf(fmaxf(ntv*ns4.x, COS_EPS));
    float c1 = acc[1] * __builtin_amdgcn_rcpf(fmaxf(ntv*ns4.y, COS_EPS));
    float c2 = acc[2] * __builtin_amdgcn_rcpf(fmaxf(ntv*ns4.z, COS_EPS));
    float c3 = acc[3] * __builtin_amdgcn_rcpf(fmaxf(ntv*ns4.w, COS_EPS));
    uint2 vv;
    vv.x = pkh2(c0, c1);
    vv.y = pkh2(c2, c3);
    *(uint2*)&cosw[(size_t)(b*MM + m)*NN + nb] = vv;
  }
}

// ---------------- K3: main. grid (64,8), 4 waves; wave w: m = mc*4 + w, mc 0..63 ----------------
// All-register; TRIPLE-buffer prefetch (A/B/C, ~3-iter load->use distance).
#define K_LD(mi, cu_, aa, ab) { \
  int mm_ = (((mi) < 64) ? (mi) : 63)*4 + w; \
  cu_ = cosP[(size_t)mm_*NN]; \
  aa = *(const uint4*)&A1H[(size_t)mm_*64 + quad*8]; \
  ab = *(const uint4*)&A1H[(size_t)mm_*64 + 32 + quad*8]; }

#define K_STEP(cu_, aa, ab) { \
  unsigned int cd_ = (cu_) | ((cu_) << 16); \
  half2v ch_ = u2h(cd_); \
  uint4 q0_, q1_; \
  q0_.x = bh1(upk[0][0], ch_, (aa).x); q0_.y = bh1(upk[0][1], ch_, (aa).y); \
  q0_.z = bh1(upk[0][2], ch_, (aa).z); q0_.w = bh1(upk[0][3], ch_, (aa).w); \
  q1_.x = bh1(upk[1][0], ch_, (ab).x); q1_.y = bh1(upk[1][1], ch_, (ab).y); \
  q1_.z = bh1(upk[1][2], ch_, (ab).z); q1_.w = bh1(upk[1][3], ch_, (ab).w); \
  half8 b0h_ = __builtin_bit_cast(half8, q0_); \
  half8 b1h_ = __builtin_bit_cast(half8, q1_); \
  f32x4 a0_, a1_, a2_, a3x_; \
  a0_ = __builtin_amdgcn_mfma_f32_16x16x32_f16(W2A[0][0], b0h_, c2v[0], 0, 0, 0); \
  a0_ = __builtin_amdgcn_mfma_f32_16x16x32_f16(W2A[0][1], b1h_, a0_, 0, 0, 0); \
  a1_ = __builtin_amdgcn_mfma_f32_16x16x32_f16(W2A[1][0], b0h_, c2v[1], 0, 0, 0); \
  a1_ = __builtin_amdgcn_mfma_f32_16x16x32_f16(W2A[1][1], b1h_, a1_, 0, 0, 0); \
  a2_ = __builtin_amdgcn_mfma_f32_16x16x32_f16(W2A[2][0], b0h_, c2v[2], 0, 0, 0); \
  a2_ = __builtin_amdgcn_mfma_f32_16x16x32_f16(W2A[2][1], b1h_, a2_, 0, 0, 0); \
  a3x_ = __builtin_amdgcn_mfma_f32_16x16x32_f16(W2A[3][0], b0h_, c2v[3], 0, 0, 0); \
  a3x_ = __builtin_amdgcn_mfma_f32_16x16x32_f16(W2A[3][1], b1h_, a3x_, 0, 0, 0); \
  e0P.x = relu2(pkh2(a0_[0], a0_[1])); e0P.y = relu2(pkh2(a0_[2], a0_[3])); \
  e0P.z = relu2(pkh2(a1_[0], a1_[1])); e0P.w = relu2(pkh2(a1_[2], a1_[3])); \
  e1P.x = relu2(pkh2(a2_[0], a2_[1])); e1P.y = relu2(pkh2(a2_[2], a2_[3])); \
  e1P.z = relu2(pkh2(a3x_[0], a3x_[1])); e1P.w = relu2(pkh2(a3x_[2], a3x_[3])); }

#define K_L3 { \
  half8 pe0_ = __builtin_bit_cast(half8, e0P); \
  half8 pe1_ = __builtin_bit_cast(half8, e1P); \
  _Pragma("unroll") \
  for (int rt = 0; rt < 4; rt++){ \
    f32x4 a3_ = __builtin_amdgcn_mfma_f32_16x16x32_f16(W3A[rt][0], pe0_, zf, 0, 0, 0); \
    a3_ = __builtin_amdgcn_mfma_f32_16x16x32_f16(W3A[rt][1], pe1_, a3_, 0, 0, 0); \
    _Pragma("unroll") \
    for (int r = 0; r < 4; r++) p[rt][r] = fmaxf(p[rt][r], a3_[r]); \
  } }

__global__ __launch_bounds__(256, 2) void k_main(const float* ws, float* Pp){
  __shared__ __align__(16) float redS[3][16][68];          // parked partials (waves 1..3)
  int t = threadIdx.x;
  int lane = t & 63, w = t >> 6;
  int ln15 = lane & 15, quad = lane >> 4;
  int b = blockIdx.y;
  int n0 = blockIdx.x * 16;

  // weight A-frags (prepacked f16; W3 slot-permuted) + layer-2 bias C (c3 deferred)
  const unsigned short* w2h = (const unsigned short*)(ws + WS_W2H);
  const unsigned short* w3h = (const unsigned short*)(ws + WS_W3H);
  half8 W2A[4][2], W3A[4][2];
  f32x4 c2v[4];
  #pragma unroll
  for (int rt = 0; rt < 4; rt++){
    int g = rt*16 + ln15;
    #pragma unroll
    for (int kk = 0; kk < 2; kk++){
      W2A[rt][kk] = *(const half8*)&w2h[g*64 + kk*32 + quad*8];
      W3A[rt][kk] = *(const half8*)&w3h[g*64 + kk*32 + quad*8];
    }
    float4 cb2 = *(const float4*)&ws[WS_C2 + rt*16 + quad*4];
    c2v[rt] = (f32x4){cb2.x, cb2.y, cb2.z, cb2.w};
  }
  f32x4 zf = (f32x4){0.f, 0.f, 0.f, 0.f};
  // u[h] packed pairs for this lane's h-chunks
  unsigned int upk[2][4];
  #pragma unroll
  for (int kk = 0; kk < 2; kk++){
    float4 ua = *(const float4*)&ws[WS_U + kk*32 + quad*8];
    float4 ub = *(const float4*)&ws[WS_U + kk*32 + quad*8 + 4];
    upk[kk][0] = pkh2(ua.x, ua.y); upk[kk][1] = pkh2(ua.z, ua.w);
    upk[kk][2] = pkh2(ub.x, ub.y); upk[kk][3] = pkh2(ub.z, ub.w);
  }
  const unsigned short* A1H = (const unsigned short*)(ws + WS_A1) + (size_t)b*MM*64;
  int n = n0 + ln15;                                // this lane's n (shared by all waves)
  const unsigned short* cosP = (const unsigned short*)(ws + WS_COSH)
                               + (size_t)b*MM*NN + n;

  f32x4 p[4];
  #pragma unroll
  for (int rt = 0; rt < 4; rt++)
    p[rt] = (f32x4){-3.0e38f, -3.0e38f, -3.0e38f, -3.0e38f};

  uint4 e0P, e1P;   // packed h2 of previous iter = L3 K32 B-frags

  // triple-buffer state: A=m(3k), B=m(3k+1), C=m(3k+2) rotation
  unsigned int cuA, cuB, cuC;
  uint4 a1aA, a1bA, a1aB, a1bB, a1aC, a1bC;

  K_LD(0, cuA, a1aA, a1bA)
  K_LD(1, cuB, a1aB, a1bB)
  K_LD(2, cuC, a1aC, a1bC)

  // iter 0: h1+L2+pack; refill A with m3 (~3-iter distance to its use)
  K_STEP(cuA, a1aA, a1bA)
  K_LD(3, cuA, a1aA, a1bA)

  // iters 1..63 in 21 triplets: m(3k+1), m(3k+2), m(3k+3); refills 3 ahead
  for (int k = 0; k < 21; k++){
    K_L3
    K_STEP(cuB, a1aB, a1bB)
    K_LD(3*k + 4, cuB, a1aB, a1bB)
    K_L3
    K_STEP(cuC, a1aC, a1bC)
    K_LD(3*k + 5, cuC, a1aC, a1bC)
    K_L3
    K_STEP(cuA, a1aA, a1bA)
    K_LD(3*k + 6, cuA, a1aA, a1bA)
  }
  // final L3 (of iter 63)
  K_L3

  // 4-way cross-wave max combine: waves 1..3 park raw p, wave 0 merges,
  // applies deferred c3 + relu, stores final P (single slice).
  __syncthreads();
  if (w >= 1){
    #pragma unroll
    for (int rt = 0; rt < 4; rt++){
      f32x4 v = p[rt];
      *(float4*)&redS[w-1][ln15][rt*16 + quad*4] = make_float4(v[0], v[1], v[2], v[3]);
    }
  }
  __syncthreads();
  if (w == 0){
    float* Pb = Pp + ((size_t)(b*NN + n) << 6);
    #pragma unroll
    for (int rt = 0; rt < 4; rt++){
      float4 o1 = *(const float4*)&redS[0][ln15][rt*16 + quad*4];
      float4 o2 = *(const float4*)&redS[1][ln15][rt*16 + quad*4];
      float4 o3 = *(const float4*)&redS[2][ln15][rt*16 + quad*4];
      float4 c3b = *(const float4*)&ws[WS_C3 + rt*16 + quad*4];
      float4 r4;
      r4.x = fmaxf(fmaxf(fmaxf(p[rt][0], o1.x), fmaxf(o2.x, o3.x)) + c3b.x, 0.f);
      r4.y = fmaxf(fmaxf(fmaxf(p[rt][1], o1.y), fmaxf(o2.y, o3.y)) + c3b.y, 0.f);
      r4.z = fmaxf(fmaxf(fmaxf(p[rt][2], o1.z), fmaxf(o2.z, o3.z)) + c3b.z, 0.f);
      r4.w = fmaxf(fmaxf(fmaxf(p[rt][3], o1.w), fmaxf(o2.w, o3.w)) + c3b.w, 0.f);
      *(float4*)&Pb[rt*16 + quad*4] = r4;
    }
  }
}

// ---------------- K4: tail (single P slice, Wc1f/relu, Wc2+bias) fp32 ----------------
__global__ __launch_bounds__(256) void k_tail(const float* Wc2, const float* bc2,
                                              const float* ws, float* out){
  __shared__ float WT[64][68];
  __shared__ float pT[32][68];
  __shared__ float cS[32][68];
  int t = threadIdx.x;
  int n0 = blockIdx.x * 32;
  int b = blockIdx.y;
  for (int i = t; i < 4096; i += 256) WT[i >> 6][i & 63] = ws[WS_WC1F + i];
  const float* P0 = ws + WS_P + ((size_t)(b*NN + n0) << 6);
  for (int i = t; i < 2048; i += 256) pT[i >> 6][i & 63] = P0[i];
  __syncthreads();
  {
    int n = t & 31, q = t >> 5;
    for (int k = 0; k < 8; k++){
      int g = q*8 + k;
      float acc = ws[WS_CC1 + g];
      for (int hs = 0; hs < 64; hs += 4){
        float4 wv = *(const float4*)&WT[g][hs];
        float4 pv = *(const float4*)&pT[n][hs];
        acc = dot4(wv, pv, acc);
      }
      cS[n][g] = fmaxf(acc, 0.f);
    }
  }
  __syncthreads();
  {
    int o = t & 127, hf = t >> 7;
    float bco = bc2[o];
    float accO[16];
    #pragma unroll
    for (int i = 0; i < 16; i++) accO[i] = bco;
    for (int hs = 0; hs < 64; hs += 4){
      float4 w4 = *(const float4*)&Wc2[o*64 + hs];
      #pragma unroll
      for (int i = 0; i < 16; i++){
        float4 cv = *(const float4*)&cS[hf*16 + i][hs];
        accO[i] = dot4(w4, cv, accO[i]);
      }
    }
    #pragma unroll
    for (int i = 0; i < 16; i++)
      out[((size_t)(b*OO + o))*NN + n0 + hf*16 + i] = accO[i];
  }
}

extern "C" void kernel_launch(void* const* d_in, const int* in_sizes, int n_in,
                              void* d_out, int out_size, void* d_ws, size_t ws_size,
                              hipStream_t stream){
  (void)in_sizes; (void)n_in; (void)out_size; (void)ws_size;
  const float* t_  = (const float*)d_in[0];
  const float* s_  = (const float*)d_in[1];
  const float* W1  = (const float*)d_in[2];
  const float* W2  = (const float*)d_in[3];
  const float* W3  = (const float*)d_in[4];
  const float* Wc1 = (const float*)d_in[5];
  const float* Wc2 = (const float*)d_in[6];
  const float* bc2 = (const float*)d_in[7];
  const float* g1 = (const float*)d_in[8],  *b1 = (const float*)d_in[9],
             * m1 = (const float*)d_in[10], *v1 = (const float*)d_in[11];
  const float* g2 = (const float*)d_in[12], *b2 = (const float*)d_in[13],
             * m2 = (const float*)d_in[14], *v2 = (const float*)d_in[15];
  const float* g3 = (const float*)d_in[16], *b3 = (const float*)d_in[17],
             * m3 = (const float*)d_in[18], *v3 = (const float*)d_in[19];
  const float* gc1 = (const float*)d_in[20], *bc1 = (const float*)d_in[21],
             * mc1 = (const float*)d_in[22], *vc1 = (const float*)d_in[23];
  float* ws = (float*)d_ws;
  float* out = (float*)d_out;

  k_prep<<<417, 256, 0, stream>>>(t_, s_, W1, W2, W3, Wc1,
      g1,b1,m1,v1, g2,b2,m2,v2, g3,b3,m3,v3, gc1,bc1,mc1,vc1, ws);
  k_cos<<<dim3(4, 16, 8), 256, 0, stream>>>(t_, s_, ws);
  k_main<<<dim3(64, 8), 256, 0, stream>>>(ws, ws + WS_P);
  k_tail<<<dim3(32, 8), 256, 0, stream>>>(Wc2, bc2, ws, out);
}